// Round 1
// baseline (979.743 us; speedup 1.0000x reference)
//
#include <hip/hip_runtime.h>
#include <hip/hip_bf16.h>
#include <stdint.h>

// Problem: E=8 experts, C=1024 tokens, H=2048 hidden, I=4096 intermediate.
//   gate_up = X @ Wgu        (E,C,H)x(E,H,2I) -> (E,C,2I)
//   act     = silu(gate)*up  -> (E,C,I)
//   out     = act @ Wd       (E,C,I)x(E,I,H) -> (E,C,H)
//
// Strategy: bf16 MFMA (16x16x32). Pre-pass converts X to bf16 and
// transposes+converts weights to [N][K] bf16 (k-contiguous) so both MFMA
// operands are loaded as 8-consecutive-k fragments (gemm_bt pattern).
// GEMM tiles: BM=128, BN=128, BK=64, 4 waves (2x2), global_load_lds width=16,
// LDS XOR swizzle (row&7 -> granule bits) applied BOTH at the pre-swizzled
// global source and the ds_read (rule #21).

#define E_  8
#define C_  1024
#define H_  2048
#define I_  4096
#define N1_ 8192   // 2*I

typedef __bf16 bf16x8 __attribute__((ext_vector_type(8)));
typedef float  f32x4  __attribute__((ext_vector_type(4)));

typedef __attribute__((address_space(3))) unsigned       lds_uint;
typedef const __attribute__((address_space(1))) unsigned glob_uint;

__device__ __forceinline__ void gload_lds16(const void* g, void* l) {
    __builtin_amdgcn_global_load_lds((glob_uint*)g, (lds_uint*)l, 16, 0, 0);
}

__device__ __forceinline__ unsigned short f2bf(float f) {
    union { float f; unsigned u; } v; v.f = f;
    unsigned u = v.u;
    return (unsigned short)((u + 0x7FFFu + ((u >> 16) & 1u)) >> 16);  // RNE
}

// ---------------- elementwise fp32 -> bf16 ----------------
__global__ void k_convert(const float* __restrict__ src,
                          unsigned short* __restrict__ dst, int n8) {
    int idx = blockIdx.x * blockDim.x + threadIdx.x;
    int stride = gridDim.x * blockDim.x;
    for (int i = idx; i < n8; i += stride) {
        const float4* s = reinterpret_cast<const float4*>(src + (size_t)i * 8);
        float4 a = s[0], b = s[1];
        ushort4 lo, hi;
        lo.x = f2bf(a.x); lo.y = f2bf(a.y); lo.z = f2bf(a.z); lo.w = f2bf(a.w);
        hi.x = f2bf(b.x); hi.y = f2bf(b.y); hi.z = f2bf(b.z); hi.w = f2bf(b.w);
        ushort4* d = reinterpret_cast<ushort4*>(dst + (size_t)i * 8);
        d[0] = lo; d[1] = hi;
    }
}

// ---------------- tiled transpose + convert: [R][Cc] f32 -> [Cc][R] bf16 ----
__global__ void k_transpose(const float* __restrict__ src,
                            unsigned short* __restrict__ dst, int R, int Cc) {
    __shared__ unsigned short tile[64][68];  // +4 pad keeps 8B alignment, spreads banks
    const int e = blockIdx.z;
    const float* s = src + (size_t)e * R * Cc;
    unsigned short* d = dst + (size_t)e * R * Cc;
    const int r0 = blockIdx.y * 64;
    const int c0 = blockIdx.x * 64;
    const int t = threadIdx.x;
    {
        int row = t >> 4;           // 0..15
        int col = (t & 15) * 4;     // 0..60
        #pragma unroll
        for (int i = 0; i < 4; ++i) {
            int rr = row + i * 16;
            float4 v = *reinterpret_cast<const float4*>(s + (size_t)(r0 + rr) * Cc + c0 + col);
            ushort4 b;
            b.x = f2bf(v.x); b.y = f2bf(v.y); b.z = f2bf(v.z); b.w = f2bf(v.w);
            *reinterpret_cast<ushort4*>(&tile[rr][col]) = b;
        }
    }
    __syncthreads();
    {
        int oc = t >> 2;   // 0..63: output row = original col
        int j  = t & 3;
        #pragma unroll
        for (int s2 = 0; s2 < 4; ++s2) {
            int orr = s2 * 16 + j * 4;
            ushort4 b;
            b.x = tile[orr + 0][oc];
            b.y = tile[orr + 1][oc];
            b.z = tile[orr + 2][oc];
            b.w = tile[orr + 3][oc];
            *reinterpret_cast<ushort4*>(d + (size_t)(c0 + oc) * R + r0 + orr) = b;
        }
    }
}

// ---------------- GEMM tile machinery ----------------
// LDS tile: logical [128 rows][64 k] bf16 = [128][128 bytes]; physical byte =
// logical ^ ((row&7)<<4).  Stage writes linearly (global_load_lds), so the
// global SOURCE address is taken at the swizzled logical position (involution).
__device__ __forceinline__ void stage_tile(const char* gbase, unsigned ld_bytes,
                                           char* lds_tile, int t) {
    const int wave = t >> 6;
    #pragma unroll
    for (int i = 0; i < 4; ++i) {
        unsigned p = (unsigned)(i * 4096 + t * 16);            // physical local byte
        unsigned q = p ^ (((p >> 7) & 7u) << 4);               // logical byte
        unsigned row = q >> 7, colb = q & 127u;
        const char* gp = gbase + (size_t)row * ld_bytes + colb;
        void* lp = lds_tile + i * 4096 + wave * 1024;          // wave-uniform base
        gload_lds16(gp, lp);
    }
}

__device__ __forceinline__ bf16x8 read_frag(const char* lds_tile, int row, int kb) {
    unsigned q = (unsigned)(row * 128 + kb);
    unsigned phys = q ^ (((q >> 7) & 7u) << 4);
    return *reinterpret_cast<const bf16x8*>(lds_tile + phys);
}

// ---------------- GEMM1: act = silu(X Wg) * (X Wu) ----------------
// X   bf16 [E][C][H]  (A operand, k=H contiguous)
// WguT bf16 [E][N1][H] (B^T, rows n, k contiguous; gate rows 0..I-1, up rows I..2I-1)
// act bf16 [E][C][I]
__global__ __launch_bounds__(256) void k_gemm1(
    const unsigned short* __restrict__ Xbf,
    const unsigned short* __restrict__ WguT,
    unsigned short* __restrict__ act) {
    __shared__ char lds[3 * 16384];
    char* As  = lds;
    char* Bgs = lds + 16384;
    char* Bus = lds + 32768;
    const int e = blockIdx.z, bm = blockIdx.y, bn = blockIdx.x;
    const int t = threadIdx.x, lane = t & 63, wave = t >> 6;
    const int wr = wave >> 1, wc = wave & 1;

    const char* Ab  = (const char*)(Xbf  + (size_t)e * C_ * H_  + (size_t)bm * 128 * H_);
    const char* Bgb = (const char*)(WguT + (size_t)e * N1_ * H_ + (size_t)bn * 128 * H_);
    const char* Bub = Bgb + (size_t)I_ * H_ * 2;  // +I rows (bytes)

    f32x4 accg[4][4] = {};
    f32x4 accu[4][4] = {};

    for (int kt = 0; kt < H_ / 64; ++kt) {
        const unsigned kb0 = kt * 128;  // byte offset along k
        stage_tile(Ab  + kb0, H_ * 2, As,  t);
        stage_tile(Bgb + kb0, H_ * 2, Bgs, t);
        stage_tile(Bub + kb0, H_ * 2, Bus, t);
        __syncthreads();
        #pragma unroll
        for (int kk = 0; kk < 2; ++kk) {
            const int kb = kk * 64 + (lane >> 4) * 16;
            bf16x8 af[4], bg[4], bu[4];
            #pragma unroll
            for (int m = 0; m < 4; ++m) af[m] = read_frag(As,  wr * 64 + m * 16 + (lane & 15), kb);
            #pragma unroll
            for (int n = 0; n < 4; ++n) bg[n] = read_frag(Bgs, wc * 64 + n * 16 + (lane & 15), kb);
            #pragma unroll
            for (int n = 0; n < 4; ++n) bu[n] = read_frag(Bus, wc * 64 + n * 16 + (lane & 15), kb);
            #pragma unroll
            for (int m = 0; m < 4; ++m)
                #pragma unroll
                for (int n = 0; n < 4; ++n) {
                    accg[m][n] = __builtin_amdgcn_mfma_f32_16x16x32_bf16(af[m], bg[n], accg[m][n], 0, 0, 0);
                    accu[m][n] = __builtin_amdgcn_mfma_f32_16x16x32_bf16(af[m], bu[n], accu[m][n], 0, 0, 0);
                }
        }
        __syncthreads();
    }

    // epilogue: silu(g)*u -> bf16
    unsigned short* actb = act + (size_t)e * C_ * I_
                         + (size_t)(bm * 128 + wr * 64) * I_ + bn * 128 + wc * 64;
    #pragma unroll
    for (int m = 0; m < 4; ++m)
        #pragma unroll
        for (int n = 0; n < 4; ++n)
            #pragma unroll
            for (int j = 0; j < 4; ++j) {
                int row = m * 16 + (lane >> 4) * 4 + j;   // C/D: col=lane&15, row=(lane>>4)*4+j
                int col = n * 16 + (lane & 15);
                float g = accg[m][n][j], u = accu[m][n][j];
                float sg = g / (1.0f + __expf(-g));
                actb[(size_t)row * I_ + col] = f2bf(sg * u);
            }
}

// ---------------- GEMM2: out = act Wd ----------------
// act bf16 [E][C][I], WdT bf16 [E][H][I] (k=I contiguous), out f32 [E][C][H]
__global__ __launch_bounds__(256) void k_gemm2(
    const unsigned short* __restrict__ act,
    const unsigned short* __restrict__ WdT,
    float* __restrict__ out) {
    __shared__ char lds[2 * 16384];
    char* As = lds;
    char* Bs = lds + 16384;
    const int e = blockIdx.z, bm = blockIdx.y, bn = blockIdx.x;
    const int t = threadIdx.x, lane = t & 63, wave = t >> 6;
    const int wr = wave >> 1, wc = wave & 1;

    const char* Ab = (const char*)(act + (size_t)e * C_ * I_ + (size_t)bm * 128 * I_);
    const char* Bb = (const char*)(WdT + (size_t)e * H_ * I_ + (size_t)bn * 128 * I_);

    f32x4 acc[4][4] = {};

    for (int kt = 0; kt < I_ / 64; ++kt) {
        const unsigned kb0 = kt * 128;
        stage_tile(Ab + kb0, I_ * 2, As, t);
        stage_tile(Bb + kb0, I_ * 2, Bs, t);
        __syncthreads();
        #pragma unroll
        for (int kk = 0; kk < 2; ++kk) {
            const int kb = kk * 64 + (lane >> 4) * 16;
            bf16x8 af[4], bf[4];
            #pragma unroll
            for (int m = 0; m < 4; ++m) af[m] = read_frag(As, wr * 64 + m * 16 + (lane & 15), kb);
            #pragma unroll
            for (int n = 0; n < 4; ++n) bf[n] = read_frag(Bs, wc * 64 + n * 16 + (lane & 15), kb);
            #pragma unroll
            for (int m = 0; m < 4; ++m)
                #pragma unroll
                for (int n = 0; n < 4; ++n)
                    acc[m][n] = __builtin_amdgcn_mfma_f32_16x16x32_bf16(af[m], bf[n], acc[m][n], 0, 0, 0);
        }
        __syncthreads();
    }

    float* ob = out + (size_t)e * C_ * H_
              + (size_t)(bm * 128 + wr * 64) * H_ + bn * 128 + wc * 64;
    #pragma unroll
    for (int m = 0; m < 4; ++m)
        #pragma unroll
        for (int n = 0; n < 4; ++n)
            #pragma unroll
            for (int j = 0; j < 4; ++j) {
                int row = m * 16 + (lane >> 4) * 4 + j;
                int col = n * 16 + (lane & 15);
                ob[(size_t)row * H_ + col] = acc[m][n][j];
            }
}

// ---------------- launch ----------------
extern "C" void kernel_launch(void* const* d_in, const int* in_sizes, int n_in,
                              void* d_out, int out_size, void* d_ws, size_t ws_size,
                              hipStream_t stream) {
    const float* hs  = (const float*)d_in[0];   // [E][C][H]
    const float* wgu = (const float*)d_in[1];   // [E][H][2I]
    const float* wd  = (const float*)d_in[2];   // [E][I][H]
    float* out = (float*)d_out;

    char* ws = (char*)d_ws;
    unsigned short* Xbf  = (unsigned short*)ws;                              //  33.55 MB
    unsigned short* WguT = (unsigned short*)(ws + 33554432ull);              // 268.44 MB
    unsigned short* WdT  = (unsigned short*)(ws + 33554432ull + 268435456ull); // 134.22 MB
    unsigned short* actb = (unsigned short*)(ws + 436207616ull);             //  67.11 MB
    // total workspace: 503,316,480 bytes

    k_convert<<<2048, 256, 0, stream>>>(hs, Xbf, E_ * C_ * H_ / 8);

    dim3 tg1(N1_ / 64, H_ / 64, E_);   // Wgu [H][2I] -> [2I][H]
    k_transpose<<<tg1, 256, 0, stream>>>(wgu, WguT, H_, N1_);

    dim3 tg2(H_ / 64, I_ / 64, E_);    // Wd [I][H] -> [H][I]
    k_transpose<<<tg2, 256, 0, stream>>>(wd, WdT, I_, H_);

    dim3 g1(I_ / 128, C_ / 128, E_);   // 32 x 8 x 8 blocks
    k_gemm1<<<g1, 256, 0, stream>>>(Xbf, WguT, actb);

    dim3 g2(H_ / 128, C_ / 128, E_);   // 16 x 8 x 8 blocks
    k_gemm2<<<g2, 256, 0, stream>>>(actb, WdT, out);
}

// Round 2
// 860.272 us; speedup vs baseline: 1.1389x; 1.1389x over previous
//
#include <hip/hip_runtime.h>
#include <stdint.h>

// E=8 experts, C=1024, H=2048, I=4096.
//   gate_up = X @ Wgu ; act = silu(gate)*up ; out = act @ Wd
// Round 2: 256x256 deep-pipelined bf16 MFMA GEMM (BK=32, 3 LDS buffers,
// counted vmcnt(4), per-phase raw s_barrier, setprio around MFMA cluster).
// GEMM1 is a plain GEMM over N=2I; silu fused into a separate elementwise pass.

#define E_  8
#define C_  1024
#define H_  2048
#define I_  4096
#define N1_ 8192   // 2*I

typedef __bf16 bf16x8 __attribute__((ext_vector_type(8)));
typedef float  f32x4  __attribute__((ext_vector_type(4)));

typedef __attribute__((address_space(3))) unsigned       lds_uint;
typedef const __attribute__((address_space(1))) unsigned glob_uint;

__device__ __forceinline__ void gload_lds16(const void* g, void* l) {
    __builtin_amdgcn_global_load_lds((glob_uint*)g, (lds_uint*)l, 16, 0, 0);
}

__device__ __forceinline__ unsigned short f2bf(float f) {
    union { float f; unsigned u; } v; v.f = f;
    unsigned u = v.u;
    return (unsigned short)((u + 0x7FFFu + ((u >> 16) & 1u)) >> 16);  // RNE
}
__device__ __forceinline__ float bf2f(unsigned short h) {
    union { unsigned u; float f; } v; v.u = (unsigned)h << 16;
    return v.f;
}

// ---------------- elementwise fp32 -> bf16 ----------------
__global__ void k_convert(const float* __restrict__ src,
                          unsigned short* __restrict__ dst, int n8) {
    int idx = blockIdx.x * blockDim.x + threadIdx.x;
    int stride = gridDim.x * blockDim.x;
    for (int i = idx; i < n8; i += stride) {
        const float4* s = reinterpret_cast<const float4*>(src + (size_t)i * 8);
        float4 a = s[0], b = s[1];
        ushort4 lo, hi;
        lo.x = f2bf(a.x); lo.y = f2bf(a.y); lo.z = f2bf(a.z); lo.w = f2bf(a.w);
        hi.x = f2bf(b.x); hi.y = f2bf(b.y); hi.z = f2bf(b.z); hi.w = f2bf(b.w);
        ushort4* d = reinterpret_cast<ushort4*>(dst + (size_t)i * 8);
        d[0] = lo; d[1] = hi;
    }
}

// ---------------- tiled transpose + convert: [R][Cc] f32 -> [Cc][R] bf16 ----
__global__ void k_transpose(const float* __restrict__ src,
                            unsigned short* __restrict__ dst, int R, int Cc) {
    __shared__ unsigned short tile[64][68];
    const int e = blockIdx.z;
    const float* s = src + (size_t)e * R * Cc;
    unsigned short* d = dst + (size_t)e * R * Cc;
    const int r0 = blockIdx.y * 64;
    const int c0 = blockIdx.x * 64;
    const int t = threadIdx.x;
    {
        int row = t >> 4;
        int col = (t & 15) * 4;
        #pragma unroll
        for (int i = 0; i < 4; ++i) {
            int rr = row + i * 16;
            float4 v = *reinterpret_cast<const float4*>(s + (size_t)(r0 + rr) * Cc + c0 + col);
            ushort4 b;
            b.x = f2bf(v.x); b.y = f2bf(v.y); b.z = f2bf(v.z); b.w = f2bf(v.w);
            *reinterpret_cast<ushort4*>(&tile[rr][col]) = b;
        }
    }
    __syncthreads();
    {
        int oc = t >> 2;
        int j  = t & 3;
        #pragma unroll
        for (int s2 = 0; s2 < 4; ++s2) {
            int orr = s2 * 16 + j * 4;
            ushort4 b;
            b.x = tile[orr + 0][oc];
            b.y = tile[orr + 1][oc];
            b.z = tile[orr + 2][oc];
            b.w = tile[orr + 3][oc];
            *reinterpret_cast<ushort4*>(d + (size_t)(c0 + oc) * R + r0 + orr) = b;
        }
    }
}

// ---------------- 256x256 deep-pipelined GEMM ----------------
// A [M][K], B [N][K], both bf16 k-contiguous, row stride LD bytes.
// LDS per buffer: A [4 kg][256 row][16B] (16 KiB) + B same (16 KiB); 3 buffers.
// 8 waves: wm=wave>>2 (2), wn=wave&3 (4); wave output 128x64.
// Per K-tile (BK=32): 2 phases x {ds_read frags, stage-issue, barrier,
// lgkmcnt(0), setprio(1), 16 MFMA, setprio(0), [vmcnt(4)], barrier}.
// 3-buffer rotation: compute t (buf t%3), t+1 resident, t+2 in flight ->
// boundary vmcnt(4) drains exactly through tile t+1.

template<int LD>
__device__ __forceinline__ void stage2(const char* __restrict__ gtile,
                                       char* ldst, int tid, int wave) {
    #pragma unroll
    for (int l = 0; l < 2; ++l) {
        unsigned p   = (unsigned)(l * 8192 + tid * 16);   // physical LDS byte (lane-linear)
        unsigned kg  = p >> 12;                           // [4][256][16] layout
        unsigned row = (p >> 4) & 255u;
        const char* gp = gtile + (size_t)row * LD + kg * 16;
        void* lp = ldst + l * 8192 + wave * 1024;         // wave-uniform base
        gload_lds16(gp, lp);
    }
}

template<int LD, int NT, bool BF16OUT>
__global__ __launch_bounds__(512, 2) void k_gemm(
    const unsigned short* __restrict__ A,
    const unsigned short* __restrict__ B,
    void* __restrict__ Cout,
    size_t sA, size_t sB, size_t sC, int ldc) {
    __shared__ char lds[3 * 32768];

    const int e = blockIdx.z, bm = blockIdx.y, bn = blockIdx.x;
    const int tid = threadIdx.x, lane = tid & 63, wave = tid >> 6;
    const int wm = wave >> 2, wn = wave & 3;
    const int kg = lane >> 4, r = lane & 15;

    const char* gA = (const char*)(A + sA * e) + (size_t)(bm * 256) * LD;
    const char* gB = (const char*)(B + sB * e) + (size_t)(bn * 256) * LD;

    // prologue: stage tiles 0 and 1
    stage2<LD>(gA,      lds,                 tid, wave);
    stage2<LD>(gB,      lds + 16384,         tid, wave);
    stage2<LD>(gA + 64, lds + 32768,         tid, wave);
    stage2<LD>(gB + 64, lds + 32768 + 16384, tid, wave);
    asm volatile("s_waitcnt vmcnt(4)" ::: "memory");
    __builtin_amdgcn_sched_barrier(0);
    __builtin_amdgcn_s_barrier();
    __builtin_amdgcn_sched_barrier(0);

    f32x4 acc[8][4] = {};
    int cur = 0;

    for (int t = 0; t < NT; ++t) {
        char* cb = lds + cur * 32768;
        const char* Ab = cb;
        const char* Bb = cb + 16384;
        const int st = (cur == 0) ? 2 : cur - 1;   // (cur+2)%3
        char* sb = lds + st * 32768;
        const size_t ko = (size_t)(t + 2) * 64;    // k byte offset of tile t+2

        // ---------------- phase 0: m0-3 ----------------
        bf16x8 aF[4], bF[4];
        #pragma unroll
        for (int m = 0; m < 4; ++m)
            aF[m] = *reinterpret_cast<const bf16x8*>(
                Ab + kg * 4096 + (size_t)(wm * 128 + m * 16 + r) * 16);
        #pragma unroll
        for (int n = 0; n < 4; ++n)
            bF[n] = *reinterpret_cast<const bf16x8*>(
                Bb + kg * 4096 + (size_t)(wn * 64 + n * 16 + r) * 16);
        if (t + 2 < NT) stage2<LD>(gA + ko, sb, tid, wave);
        __builtin_amdgcn_sched_barrier(0);
        __builtin_amdgcn_s_barrier();
        asm volatile("s_waitcnt lgkmcnt(0)" ::: "memory");
        __builtin_amdgcn_sched_barrier(0);
        __builtin_amdgcn_s_setprio(1);
        #pragma unroll
        for (int m = 0; m < 4; ++m)
            #pragma unroll
            for (int n = 0; n < 4; ++n)
                acc[m][n] = __builtin_amdgcn_mfma_f32_16x16x32_bf16(
                    aF[m], bF[n], acc[m][n], 0, 0, 0);
        __builtin_amdgcn_s_setprio(0);
        __builtin_amdgcn_sched_barrier(0);
        __builtin_amdgcn_s_barrier();
        __builtin_amdgcn_sched_barrier(0);

        // ---------------- phase 1: m4-7 ----------------
        bf16x8 aG[4];
        #pragma unroll
        for (int m = 0; m < 4; ++m)
            aG[m] = *reinterpret_cast<const bf16x8*>(
                Ab + kg * 4096 + (size_t)(wm * 128 + (m + 4) * 16 + r) * 16);
        if (t + 2 < NT) stage2<LD>(gB + ko, sb + 16384, tid, wave);
        __builtin_amdgcn_sched_barrier(0);
        __builtin_amdgcn_s_barrier();
        asm volatile("s_waitcnt lgkmcnt(0)" ::: "memory");
        __builtin_amdgcn_sched_barrier(0);
        __builtin_amdgcn_s_setprio(1);
        #pragma unroll
        for (int m = 0; m < 4; ++m)
            #pragma unroll
            for (int n = 0; n < 4; ++n)
                acc[m + 4][n] = __builtin_amdgcn_mfma_f32_16x16x32_bf16(
                    aG[m], bF[n], acc[m + 4][n], 0, 0, 0);
        __builtin_amdgcn_s_setprio(0);
        __builtin_amdgcn_sched_barrier(0);
        if (t == NT - 2) { asm volatile("s_waitcnt vmcnt(0)" ::: "memory"); }
        else             { asm volatile("s_waitcnt vmcnt(4)" ::: "memory"); }
        __builtin_amdgcn_sched_barrier(0);
        __builtin_amdgcn_s_barrier();
        __builtin_amdgcn_sched_barrier(0);

        cur = (cur == 2) ? 0 : cur + 1;
    }

    // ---------------- epilogue ----------------
    const int orow0 = bm * 256 + wm * 128 + kg * 4;  // + m*16 + j
    const int ocol0 = bn * 256 + wn * 64 + r;        // + n*16
    if constexpr (BF16OUT) {
        unsigned short* Cp = (unsigned short*)Cout + sC * e;
        #pragma unroll
        for (int m = 0; m < 8; ++m)
            #pragma unroll
            for (int n = 0; n < 4; ++n)
                #pragma unroll
                for (int j = 0; j < 4; ++j)
                    Cp[(size_t)(orow0 + m * 16 + j) * ldc + ocol0 + n * 16] =
                        f2bf(acc[m][n][j]);
    } else {
        float* Cp = (float*)Cout + sC * e;
        #pragma unroll
        for (int m = 0; m < 8; ++m)
            #pragma unroll
            for (int n = 0; n < 4; ++n)
                #pragma unroll
                for (int j = 0; j < 4; ++j)
                    Cp[(size_t)(orow0 + m * 16 + j) * ldc + ocol0 + n * 16] =
                        acc[m][n][j];
    }
}

// ---------------- silu(gate)*up: [EC][2I] bf16 -> [EC][I] bf16 ----------------
__global__ void k_silu(const unsigned short* __restrict__ gu,
                       unsigned short* __restrict__ act, int n8) {
    int idx = blockIdx.x * blockDim.x + threadIdx.x;
    int stride = gridDim.x * blockDim.x;
    for (int i = idx; i < n8; i += stride) {
        int rowc = i >> 9;              // I/8 = 512 chunks per row
        int ic   = (i & 511) * 8;
        const ushort4* gp = reinterpret_cast<const ushort4*>(gu + (size_t)rowc * N1_ + ic);
        const ushort4* up = reinterpret_cast<const ushort4*>(gu + (size_t)rowc * N1_ + I_ + ic);
        ushort4 g0 = gp[0], g1 = gp[1], u0 = up[0], u1 = up[1];
        ushort4 o0, o1;
        float g, u;
        g = bf2f(g0.x); u = bf2f(u0.x); o0.x = f2bf(g / (1.0f + __expf(-g)) * u);
        g = bf2f(g0.y); u = bf2f(u0.y); o0.y = f2bf(g / (1.0f + __expf(-g)) * u);
        g = bf2f(g0.z); u = bf2f(u0.z); o0.z = f2bf(g / (1.0f + __expf(-g)) * u);
        g = bf2f(g0.w); u = bf2f(u0.w); o0.w = f2bf(g / (1.0f + __expf(-g)) * u);
        g = bf2f(g1.x); u = bf2f(u1.x); o1.x = f2bf(g / (1.0f + __expf(-g)) * u);
        g = bf2f(g1.y); u = bf2f(u1.y); o1.y = f2bf(g / (1.0f + __expf(-g)) * u);
        g = bf2f(g1.z); u = bf2f(u1.z); o1.z = f2bf(g / (1.0f + __expf(-g)) * u);
        g = bf2f(g1.w); u = bf2f(u1.w); o1.w = f2bf(g / (1.0f + __expf(-g)) * u);
        ushort4* d = reinterpret_cast<ushort4*>(act + (size_t)rowc * I_ + ic);
        d[0] = o0; d[1] = o1;
    }
}

// ---------------- launch ----------------
extern "C" void kernel_launch(void* const* d_in, const int* in_sizes, int n_in,
                              void* d_out, int out_size, void* d_ws, size_t ws_size,
                              hipStream_t stream) {
    const float* hs  = (const float*)d_in[0];   // [E][C][H]
    const float* wgu = (const float*)d_in[1];   // [E][H][2I]
    const float* wd  = (const float*)d_in[2];   // [E][I][H]
    float* out = (float*)d_out;

    char* ws = (char*)d_ws;
    unsigned short* Xbf  = (unsigned short*)(ws);                 //  33,554,432
    unsigned short* WguT = (unsigned short*)(ws +  33554432ull);  // 268,435,456
    unsigned short* actb = (unsigned short*)(ws + 301989888ull);  //  67,108,864
    unsigned short* guWd = (unsigned short*)(ws + 369098752ull);  // 134,217,728 (gate_up, then WdT)
    // total: 503,316,480 bytes (same footprint as round 1)

    k_convert<<<2048, 256, 0, stream>>>(hs, Xbf, E_ * C_ * H_ / 8);

    dim3 tg1(N1_ / 64, H_ / 64, E_);   // Wgu [H][2I] -> WguT [2I][H]
    k_transpose<<<tg1, 256, 0, stream>>>(wgu, WguT, H_, N1_);

    // GEMM1: [EC][H] x [2I][H] -> gate_up [EC][2I]  (K=2048, NT=64)
    dim3 g1(N1_ / 256, C_ / 256, E_);  // 32 x 4 x 8
    k_gemm<H_ * 2, H_ / 32, true><<<g1, 512, 0, stream>>>(
        Xbf, WguT, guWd,
        (size_t)C_ * H_, (size_t)N1_ * H_, (size_t)C_ * N1_, N1_);

    k_silu<<<2048, 256, 0, stream>>>(guWd, actb, E_ * C_ * I_ / 8);

    dim3 tg2(H_ / 64, I_ / 64, E_);    // Wd [I][H] -> WdT [H][I]  (reuses gate_up region)
    k_transpose<<<tg2, 256, 0, stream>>>(wd, guWd, I_, H_);

    // GEMM2: [EC][I] x [H][I] -> out f32 [EC][H]  (K=4096, NT=128)
    dim3 g2(H_ / 256, C_ / 256, E_);   // 8 x 4 x 8
    k_gemm<I_ * 2, I_ / 32, false><<<g2, 512, 0, stream>>>(
        actb, guWd, out,
        (size_t)C_ * I_, (size_t)H_ * I_, (size_t)C_ * H_, H_);
}

// Round 3
// 703.156 us; speedup vs baseline: 1.3934x; 1.2234x over previous
//
#include <hip/hip_runtime.h>
#include <stdint.h>

// E=8 experts, C=1024, H=2048, I=4096.
//   gate_up = X @ Wgu ; act = silu(gate)*up ; out = act @ Wd
// Round 3: identical sync structure to round 2 (256x256 tile, BK=32, 3 LDS
// buffers, counted vmcnt(4), setprio). ONLY change: LDS tile layout is now
// row-major [256 rows][64B] with XOR swizzle kb^=(row&3)<<4, applied as the
// same involution on the pre-swizzled global source (stage) and on ds_read.
// This makes each global_load_lds cover 16 rows x 64B contiguous segments
// (coalesced) instead of 64 scattered 16B requests, while keeping ds_read
// bank-conflict-free (2-way max = free).

#define E_  8
#define C_  1024
#define H_  2048
#define I_  4096
#define N1_ 8192   // 2*I

typedef __bf16 bf16x8 __attribute__((ext_vector_type(8)));
typedef float  f32x4  __attribute__((ext_vector_type(4)));

typedef __attribute__((address_space(3))) unsigned       lds_uint;
typedef const __attribute__((address_space(1))) unsigned glob_uint;

__device__ __forceinline__ void gload_lds16(const void* g, void* l) {
    __builtin_amdgcn_global_load_lds((glob_uint*)g, (lds_uint*)l, 16, 0, 0);
}

__device__ __forceinline__ unsigned short f2bf(float f) {
    union { float f; unsigned u; } v; v.f = f;
    unsigned u = v.u;
    return (unsigned short)((u + 0x7FFFu + ((u >> 16) & 1u)) >> 16);  // RNE
}
__device__ __forceinline__ float bf2f(unsigned short h) {
    union { unsigned u; float f; } v; v.u = (unsigned)h << 16;
    return v.f;
}

// ---------------- elementwise fp32 -> bf16 ----------------
__global__ void k_convert(const float* __restrict__ src,
                          unsigned short* __restrict__ dst, int n8) {
    int idx = blockIdx.x * blockDim.x + threadIdx.x;
    int stride = gridDim.x * blockDim.x;
    for (int i = idx; i < n8; i += stride) {
        const float4* s = reinterpret_cast<const float4*>(src + (size_t)i * 8);
        float4 a = s[0], b = s[1];
        ushort4 lo, hi;
        lo.x = f2bf(a.x); lo.y = f2bf(a.y); lo.z = f2bf(a.z); lo.w = f2bf(a.w);
        hi.x = f2bf(b.x); hi.y = f2bf(b.y); hi.z = f2bf(b.z); hi.w = f2bf(b.w);
        ushort4* d = reinterpret_cast<ushort4*>(dst + (size_t)i * 8);
        d[0] = lo; d[1] = hi;
    }
}

// ---------------- tiled transpose + convert: [R][Cc] f32 -> [Cc][R] bf16 ----
__global__ void k_transpose(const float* __restrict__ src,
                            unsigned short* __restrict__ dst, int R, int Cc) {
    __shared__ unsigned short tile[64][68];
    const int e = blockIdx.z;
    const float* s = src + (size_t)e * R * Cc;
    unsigned short* d = dst + (size_t)e * R * Cc;
    const int r0 = blockIdx.y * 64;
    const int c0 = blockIdx.x * 64;
    const int t = threadIdx.x;
    {
        int row = t >> 4;
        int col = (t & 15) * 4;
        #pragma unroll
        for (int i = 0; i < 4; ++i) {
            int rr = row + i * 16;
            float4 v = *reinterpret_cast<const float4*>(s + (size_t)(r0 + rr) * Cc + c0 + col);
            ushort4 b;
            b.x = f2bf(v.x); b.y = f2bf(v.y); b.z = f2bf(v.z); b.w = f2bf(v.w);
            *reinterpret_cast<ushort4*>(&tile[rr][col]) = b;
        }
    }
    __syncthreads();
    {
        int oc = t >> 2;
        int j  = t & 3;
        #pragma unroll
        for (int s2 = 0; s2 < 4; ++s2) {
            int orr = s2 * 16 + j * 4;
            ushort4 b;
            b.x = tile[orr + 0][oc];
            b.y = tile[orr + 1][oc];
            b.z = tile[orr + 2][oc];
            b.w = tile[orr + 3][oc];
            *reinterpret_cast<ushort4*>(d + (size_t)(c0 + oc) * R + r0 + orr) = b;
        }
    }
}

// ---------------- 256x256 deep-pipelined GEMM ----------------
// A [M][K], B [N][K], both bf16 k-contiguous, row stride LD bytes.
// LDS per buffer: A [256 row][64B] (16 KiB, XOR-swizzled) + B same; 3 buffers.
// 8 waves: wm=wave>>2 (2), wn=wave&3 (4); wave output 128x64.
// Per K-tile (BK=32): 2 phases x {ds_read frags, stage-issue, barrier,
// lgkmcnt(0), setprio(1), 16 MFMA, setprio(0), [vmcnt(4)], barrier}.
// 3-buffer rotation: compute t (buf t%3), t+1 resident, t+2 in flight ->
// boundary vmcnt(4) drains exactly through tile t+1.

template<int LD>
__device__ __forceinline__ void stage2(const char* __restrict__ gtile,
                                       char* ldst, int tid, int wave) {
    #pragma unroll
    for (int l = 0; l < 2; ++l) {
        unsigned p   = (unsigned)(l * 8192 + tid * 16);   // physical LDS byte (lane-linear)
        unsigned row = p >> 6;                            // [256 rows][64B]
        unsigned kb  = (p & 63u) ^ ((row & 3u) << 4);     // logical k-byte (involution)
        const char* gp = gtile + (size_t)row * LD + kb;
        void* lp = ldst + l * 8192 + wave * 1024;         // wave-uniform base
        gload_lds16(gp, lp);
    }
}

// logical (row, kg) -> physical swizzled address
__device__ __forceinline__ const bf16x8* frag_at(const char* lds_tile, int row, int kbl) {
    unsigned phys = (unsigned)(row * 64) + ((unsigned)kbl ^ (((unsigned)row & 3u) << 4));
    return reinterpret_cast<const bf16x8*>(lds_tile + phys);
}

template<int LD, int NT, bool BF16OUT>
__global__ __launch_bounds__(512, 2) void k_gemm(
    const unsigned short* __restrict__ A,
    const unsigned short* __restrict__ B,
    void* __restrict__ Cout,
    size_t sA, size_t sB, size_t sC, int ldc) {
    __shared__ char lds[3 * 32768];

    const int e = blockIdx.z, bm = blockIdx.y, bn = blockIdx.x;
    const int tid = threadIdx.x, lane = tid & 63, wave = tid >> 6;
    const int wm = wave >> 2, wn = wave & 3;
    const int kg = lane >> 4, r = lane & 15;
    const int kbl = kg * 16;   // logical k-byte of this lane's fragment

    const char* gA = (const char*)(A + sA * e) + (size_t)(bm * 256) * LD;
    const char* gB = (const char*)(B + sB * e) + (size_t)(bn * 256) * LD;

    // prologue: stage tiles 0 and 1
    stage2<LD>(gA,      lds,                 tid, wave);
    stage2<LD>(gB,      lds + 16384,         tid, wave);
    stage2<LD>(gA + 64, lds + 32768,         tid, wave);
    stage2<LD>(gB + 64, lds + 32768 + 16384, tid, wave);
    asm volatile("s_waitcnt vmcnt(4)" ::: "memory");
    __builtin_amdgcn_sched_barrier(0);
    __builtin_amdgcn_s_barrier();
    __builtin_amdgcn_sched_barrier(0);

    f32x4 acc[8][4] = {};
    int cur = 0;

    for (int t = 0; t < NT; ++t) {
        char* cb = lds + cur * 32768;
        const char* Ab = cb;
        const char* Bb = cb + 16384;
        const int st = (cur == 0) ? 2 : cur - 1;   // (cur+2)%3
        char* sb = lds + st * 32768;
        const size_t ko = (size_t)(t + 2) * 64;    // k byte offset of tile t+2

        // ---------------- phase 0: m0-3 ----------------
        bf16x8 aF[4], bF[4];
        #pragma unroll
        for (int m = 0; m < 4; ++m)
            aF[m] = *frag_at(Ab, wm * 128 + m * 16 + r, kbl);
        #pragma unroll
        for (int n = 0; n < 4; ++n)
            bF[n] = *frag_at(Bb, wn * 64 + n * 16 + r, kbl);
        if (t + 2 < NT) stage2<LD>(gA + ko, sb, tid, wave);
        __builtin_amdgcn_sched_barrier(0);
        __builtin_amdgcn_s_barrier();
        asm volatile("s_waitcnt lgkmcnt(0)" ::: "memory");
        __builtin_amdgcn_sched_barrier(0);
        __builtin_amdgcn_s_setprio(1);
        #pragma unroll
        for (int m = 0; m < 4; ++m)
            #pragma unroll
            for (int n = 0; n < 4; ++n)
                acc[m][n] = __builtin_amdgcn_mfma_f32_16x16x32_bf16(
                    aF[m], bF[n], acc[m][n], 0, 0, 0);
        __builtin_amdgcn_s_setprio(0);
        __builtin_amdgcn_sched_barrier(0);
        __builtin_amdgcn_s_barrier();
        __builtin_amdgcn_sched_barrier(0);

        // ---------------- phase 1: m4-7 ----------------
        bf16x8 aG[4];
        #pragma unroll
        for (int m = 0; m < 4; ++m)
            aG[m] = *frag_at(Ab, wm * 128 + (m + 4) * 16 + r, kbl);
        if (t + 2 < NT) stage2<LD>(gB + ko, sb + 16384, tid, wave);
        __builtin_amdgcn_sched_barrier(0);
        __builtin_amdgcn_s_barrier();
        asm volatile("s_waitcnt lgkmcnt(0)" ::: "memory");
        __builtin_amdgcn_sched_barrier(0);
        __builtin_amdgcn_s_setprio(1);
        #pragma unroll
        for (int m = 0; m < 4; ++m)
            #pragma unroll
            for (int n = 0; n < 4; ++n)
                acc[m + 4][n] = __builtin_amdgcn_mfma_f32_16x16x32_bf16(
                    aG[m], bF[n], acc[m + 4][n], 0, 0, 0);
        __builtin_amdgcn_s_setprio(0);
        __builtin_amdgcn_sched_barrier(0);
        if (t == NT - 2) { asm volatile("s_waitcnt vmcnt(0)" ::: "memory"); }
        else             { asm volatile("s_waitcnt vmcnt(4)" ::: "memory"); }
        __builtin_amdgcn_sched_barrier(0);
        __builtin_amdgcn_s_barrier();
        __builtin_amdgcn_sched_barrier(0);

        cur = (cur == 2) ? 0 : cur + 1;
    }

    // ---------------- epilogue ----------------
    const int orow0 = bm * 256 + wm * 128 + kg * 4;  // + m*16 + j
    const int ocol0 = bn * 256 + wn * 64 + r;        // + n*16
    if constexpr (BF16OUT) {
        unsigned short* Cp = (unsigned short*)Cout + sC * e;
        #pragma unroll
        for (int m = 0; m < 8; ++m)
            #pragma unroll
            for (int n = 0; n < 4; ++n)
                #pragma unroll
                for (int j = 0; j < 4; ++j)
                    Cp[(size_t)(orow0 + m * 16 + j) * ldc + ocol0 + n * 16] =
                        f2bf(acc[m][n][j]);
    } else {
        float* Cp = (float*)Cout + sC * e;
        #pragma unroll
        for (int m = 0; m < 8; ++m)
            #pragma unroll
            for (int n = 0; n < 4; ++n)
                #pragma unroll
                for (int j = 0; j < 4; ++j)
                    Cp[(size_t)(orow0 + m * 16 + j) * ldc + ocol0 + n * 16] =
                        acc[m][n][j];
    }
}

// ---------------- silu(gate)*up: [EC][2I] bf16 -> [EC][I] bf16 ----------------
__global__ void k_silu(const unsigned short* __restrict__ gu,
                       unsigned short* __restrict__ act, int n8) {
    int idx = blockIdx.x * blockDim.x + threadIdx.x;
    int stride = gridDim.x * blockDim.x;
    for (int i = idx; i < n8; i += stride) {
        int rowc = i >> 9;              // I/8 = 512 chunks per row
        int ic   = (i & 511) * 8;
        const ushort4* gp = reinterpret_cast<const ushort4*>(gu + (size_t)rowc * N1_ + ic);
        const ushort4* up = reinterpret_cast<const ushort4*>(gu + (size_t)rowc * N1_ + I_ + ic);
        ushort4 g0 = gp[0], g1 = gp[1], u0 = up[0], u1 = up[1];
        ushort4 o0, o1;
        float g, u;
        g = bf2f(g0.x); u = bf2f(u0.x); o0.x = f2bf(g / (1.0f + __expf(-g)) * u);
        g = bf2f(g0.y); u = bf2f(u0.y); o0.y = f2bf(g / (1.0f + __expf(-g)) * u);
        g = bf2f(g0.z); u = bf2f(u0.z); o0.z = f2bf(g / (1.0f + __expf(-g)) * u);
        g = bf2f(g0.w); u = bf2f(u0.w); o0.w = f2bf(g / (1.0f + __expf(-g)) * u);
        g = bf2f(g1.x); u = bf2f(u1.x); o1.x = f2bf(g / (1.0f + __expf(-g)) * u);
        g = bf2f(g1.y); u = bf2f(u1.y); o1.y = f2bf(g / (1.0f + __expf(-g)) * u);
        g = bf2f(g1.z); u = bf2f(u1.z); o1.z = f2bf(g / (1.0f + __expf(-g)) * u);
        g = bf2f(g1.w); u = bf2f(u1.w); o1.w = f2bf(g / (1.0f + __expf(-g)) * u);
        ushort4* d = reinterpret_cast<ushort4*>(act + (size_t)rowc * I_ + ic);
        d[0] = o0; d[1] = o1;
    }
}

// ---------------- launch ----------------
extern "C" void kernel_launch(void* const* d_in, const int* in_sizes, int n_in,
                              void* d_out, int out_size, void* d_ws, size_t ws_size,
                              hipStream_t stream) {
    const float* hs  = (const float*)d_in[0];   // [E][C][H]
    const float* wgu = (const float*)d_in[1];   // [E][H][2I]
    const float* wd  = (const float*)d_in[2];   // [E][I][H]
    float* out = (float*)d_out;

    char* ws = (char*)d_ws;
    unsigned short* Xbf  = (unsigned short*)(ws);                 //  33,554,432
    unsigned short* WguT = (unsigned short*)(ws +  33554432ull);  // 268,435,456
    unsigned short* actb = (unsigned short*)(ws + 301989888ull);  //  67,108,864
    unsigned short* guWd = (unsigned short*)(ws + 369098752ull);  // 134,217,728 (gate_up, then WdT)
    // total: 503,316,480 bytes

    k_convert<<<2048, 256, 0, stream>>>(hs, Xbf, E_ * C_ * H_ / 8);

    dim3 tg1(N1_ / 64, H_ / 64, E_);   // Wgu [H][2I] -> WguT [2I][H]
    k_transpose<<<tg1, 256, 0, stream>>>(wgu, WguT, H_, N1_);

    // GEMM1: [EC][H] x [2I][H] -> gate_up [EC][2I]  (K=2048, NT=64)
    dim3 g1(N1_ / 256, C_ / 256, E_);  // 32 x 4 x 8
    k_gemm<H_ * 2, H_ / 32, true><<<g1, 512, 0, stream>>>(
        Xbf, WguT, guWd,
        (size_t)C_ * H_, (size_t)N1_ * H_, (size_t)C_ * N1_, N1_);

    k_silu<<<2048, 256, 0, stream>>>(guWd, actb, E_ * C_ * I_ / 8);

    dim3 tg2(H_ / 64, I_ / 64, E_);    // Wd [I][H] -> WdT [H][I]  (reuses gate_up region)
    k_transpose<<<tg2, 256, 0, stream>>>(wd, guWd, I_, H_);

    // GEMM2: [EC][I] x [H][I] -> out f32 [EC][H]  (K=4096, NT=128)
    dim3 g2(H_ / 256, C_ / 256, E_);   // 8 x 4 x 8
    k_gemm<I_ * 2, I_ / 32, false><<<g2, 512, 0, stream>>>(
        actb, guWd, out,
        (size_t)C_ * I_, (size_t)H_ * I_, (size_t)C_ * H_, H_);
}